// Round 4
// baseline (104.974 us; speedup 1.0000x reference)
//
#include <hip/hip_runtime.h>
#include <math.h>

// PLIF (parametric LIF) forward, heterogeneous per-feature decay/threshold.
// x: [B=4, N=1024, T=128, D=128] fp32, sequential scan over T per (b,n,d):
//   v = v * sigmoid(decay[d]) + x[t]
//   s = (v > sigmoid(v_th[d]) + 0.1) ? 1 : 0
//   v = s ? 0 : v        (hard reset; exact since s in {0,1})
//
// R4: manual register double-buffer across unroll blocks of 8 time-steps.
//     Named bufA/bufB (NOT buf[2][8] -- runtime-indexed ext_vector arrays
//     spill to scratch, rule #20). Prefetch block b+1 before computing
//     block b, so each wave keeps 8 loads in flight ACROSS block
//     boundaries instead of draining at each boundary (the R3 limiter:
//     5.15 TB/s = 82% of copy ceiling).
//     Kept from R3: float2/thread (4 waves/SIMD), nontemporal load/store
//     (streaming 512 MB once; don't pollute 256 MB L3).
//
// __fmul_rn/__fadd_rn prevent fma contraction so fp32 rounding matches the
// mul-then-add numpy reference exactly (spike compares are boundary-
// sensitive: one ulp flip -> absmax 1.0). R1/R3 passed with absmax 0.0.

#define T_STEPS 128
#define D_FEAT  128
#define GROUPS  (D_FEAT / 2)   // 64 float2 groups per (b,n) row
#define UB      8              // time-steps per unroll block
#define NB      (T_STEPS / UB) // 16 blocks

typedef float f32x2 __attribute__((ext_vector_type(2)));

__global__ __launch_bounds__(256)
void plif_fwd_kernel(const f32x2* __restrict__ x,
                     const float* __restrict__ decay,
                     const float* __restrict__ vth,
                     f32x2* __restrict__ out)
{
    const int tid = blockIdx.x * blockDim.x + threadIdx.x;
    const int g   = tid & (GROUPS - 1);   // float2 group within D
    const int row = tid >> 6;             // b*N + n

    const size_t base = (size_t)row * (size_t)T_STEPS * GROUPS + (size_t)g;
    const f32x2* __restrict__ xr  = x + base;
    f32x2* __restrict__       orw = out + base;

    // per-feature constants (4 expf per thread -- negligible)
    const int d0 = g * 2;
    const float dec0 = 1.0f / (1.0f + expf(-decay[d0 + 0]));
    const float dec1 = 1.0f / (1.0f + expf(-decay[d0 + 1]));
    const float th0  = 1.0f / (1.0f + expf(-vth[d0 + 0])) + 0.1f;
    const float th1  = 1.0f / (1.0f + expf(-vth[d0 + 1])) + 0.1f;

    float v0 = 0.0f, v1 = 0.0f;

    f32x2 bufA[UB], bufB[UB];

    // prefetch block 0 into bufA
#pragma unroll
    for (int i = 0; i < UB; ++i)
        bufA[i] = __builtin_nontemporal_load(xr + (size_t)i * GROUPS);

#define COMPUTE_STORE(BUF, BLK)                                          \
    do {                                                                 \
        _Pragma("unroll")                                                \
        for (int i = 0; i < UB; ++i) {                                   \
            const int t = (BLK) * UB + i;                                \
            const f32x2 xv = BUF[i];                                     \
            v0 = __fadd_rn(__fmul_rn(v0, dec0), xv.x);                   \
            const bool fa = (v0 > th0);                                  \
            const float sa = fa ? 1.0f : 0.0f;                           \
            v0 = fa ? 0.0f : v0;                                         \
            v1 = __fadd_rn(__fmul_rn(v1, dec1), xv.y);                   \
            const bool fb = (v1 > th1);                                  \
            const float sb = fb ? 1.0f : 0.0f;                           \
            v1 = fb ? 0.0f : v1;                                         \
            f32x2 sv; sv.x = sa; sv.y = sb;                              \
            __builtin_nontemporal_store(sv, orw + (size_t)t * GROUPS);   \
        }                                                                \
    } while (0)

#define PREFETCH(BUF, BLK)                                               \
    do {                                                                 \
        _Pragma("unroll")                                                \
        for (int i = 0; i < UB; ++i)                                     \
            BUF[i] = __builtin_nontemporal_load(                         \
                xr + (size_t)((BLK) * UB + i) * GROUPS);                 \
    } while (0)

#pragma unroll
    for (int b = 0; b < NB; b += 2) {
        // issue block b+1 loads before consuming block b
        if (b + 1 < NB) PREFETCH(bufB, b + 1);
        COMPUTE_STORE(bufA, b);
        if (b + 2 < NB) PREFETCH(bufA, b + 2);
        COMPUTE_STORE(bufB, b + 1);
    }

#undef COMPUTE_STORE
#undef PREFETCH
}

extern "C" void kernel_launch(void* const* d_in, const int* in_sizes, int n_in,
                              void* d_out, int out_size, void* d_ws, size_t ws_size,
                              hipStream_t stream)
{
    const float* x     = (const float*)d_in[0];
    const float* decay = (const float*)d_in[1];
    const float* vth   = (const float*)d_in[2];
    float*       out   = (float*)d_out;

    const int total   = in_sizes[0];                    // B*N*T*D = 67108864
    const int rows    = total / (T_STEPS * D_FEAT);     // B*N = 4096
    const int threads = rows * GROUPS;                  // 262144
    const int block   = 256;

    plif_fwd_kernel<<<threads / block, block, 0, stream>>>(
        (const f32x2*)x, decay, vth, (f32x2*)out);
}

// Round 5
// 102.539 us; speedup vs baseline: 1.0237x; 1.0237x over previous
//
#include <hip/hip_runtime.h>
#include <math.h>

// PLIF (parametric LIF) forward, heterogeneous per-feature decay/threshold.
// x: [B=4, N=1024, T=128, D=128] fp32, sequential scan over T per (b,n,d):
//   v = v * sigmoid(decay[d]) + x[t]
//   s = (v > sigmoid(v_th[d]) + 0.1) ? 1 : 0
//   v = s ? 0 : v        (hard reset; exact since s in {0,1})
//
// R5: scalar-per-thread for max occupancy. 524288 threads = 2048 blocks =
//     8 blocks/CU = 32 waves/CU = 8 waves/SIMD (2x R3's 4). Wave access is
//     still fully coalesced: 64 lanes x 4B = 256B contiguous per step.
//     R4's manual double-buffer was NEUTRAL (compiler already batches the
//     unrolled loads) -> back to the simple loop, unroll 16.
//     Kept: nontemporal load/store (512 MB streamed once; don't pollute L3).
//
// __fmul_rn/__fadd_rn prevent fma contraction so fp32 rounding matches the
// mul-then-add numpy reference exactly (spike compares are boundary-
// sensitive: one ulp flip -> absmax 1.0). R1/R3/R4 passed with absmax 0.0.

#define T_STEPS 128
#define D_FEAT  128

__global__ __launch_bounds__(256)
void plif_fwd_kernel(const float* __restrict__ x,
                     const float* __restrict__ decay,
                     const float* __restrict__ vth,
                     float* __restrict__ out)
{
    const int tid = blockIdx.x * blockDim.x + threadIdx.x;
    const int d   = tid & (D_FEAT - 1);   // feature index
    const int row = tid >> 7;             // b*N + n

    const size_t base = (size_t)row * (size_t)T_STEPS * D_FEAT + (size_t)d;
    const float* __restrict__ xr  = x + base;
    float* __restrict__       orw = out + base;

    // per-feature constants (2 expf per thread -- negligible)
    const float dec = 1.0f / (1.0f + expf(-decay[d]));
    const float th  = 1.0f / (1.0f + expf(-vth[d])) + 0.1f;

    float v = 0.0f;

#pragma unroll 16
    for (int t = 0; t < T_STEPS; ++t) {
        const float xv = __builtin_nontemporal_load(xr + (size_t)t * D_FEAT);

        v = __fadd_rn(__fmul_rn(v, dec), xv);
        const bool f = (v > th);
        const float s = f ? 1.0f : 0.0f;
        v = f ? 0.0f : v;

        __builtin_nontemporal_store(s, orw + (size_t)t * D_FEAT);
    }
}

extern "C" void kernel_launch(void* const* d_in, const int* in_sizes, int n_in,
                              void* d_out, int out_size, void* d_ws, size_t ws_size,
                              hipStream_t stream)
{
    const float* x     = (const float*)d_in[0];
    const float* decay = (const float*)d_in[1];
    const float* vth   = (const float*)d_in[2];
    float*       out   = (float*)d_out;

    const int total   = in_sizes[0];                    // B*N*T*D = 67108864
    const int rows    = total / (T_STEPS * D_FEAT);     // B*N = 4096
    const int threads = rows * D_FEAT;                  // 524288
    const int block   = 256;

    plif_fwd_kernel<<<threads / block, block, 0, stream>>>(
        x, decay, vth, out);
}

// Round 6
// 94.360 us; speedup vs baseline: 1.1125x; 1.0867x over previous
//
#include <hip/hip_runtime.h>
#include <math.h>

// PLIF (parametric LIF) forward, heterogeneous per-feature decay/threshold.
// x: [B=4, N=1024, T=128, D=128] fp32, sequential scan over T per (b,n,d):
//   v = v * sigmoid(decay[d]) + x[t]
//   s = (v > sigmoid(v_th[d]) + 0.1) ? 1 : 0
//   v = s ? 0 : v        (hard reset; exact since s in {0,1})
//
// R6: decouple HBM access width from compute mapping via LDS staging.
//     R5 (scalar, 8 waves/SIMD) hit 5.24 TB/s = 83% of copy ceiling; its
//     wave-instructions touch only 256B (vs copy bench's 1024B). Here each
//     256-thread block owns 2 rows; per 8-step chunk it stages x via
//     fully-contiguous float4 loads (1024B/wave-instr, copy-identical
//     pattern), computes scalar chains from LDS (stride-4B = 2-way bank
//     aliasing = free), and stores spikes back as contiguous float4.
//     16KB LDS x 8 blocks/CU = 128KB <= 160KB -> full occupancy retained.
//     R4 lesson: compiler already schedules loads well; the change here is
//     the HBM *pattern*, not scheduling.
//
// __fmul_rn/__fadd_rn prevent fma contraction so fp32 rounding matches the
// mul-then-add numpy reference exactly (spike compares are boundary-
// sensitive: one ulp flip -> absmax 1.0). R1/R3/R4/R5 passed absmax 0.0.

#define T_STEPS 128
#define D_FEAT  128
#define CT      8                 // time-steps per staged chunk
#define NCHUNK  (T_STEPS / CT)    // 16 chunks

typedef float f32x4 __attribute__((ext_vector_type(4)));

__global__ __launch_bounds__(256)
void plif_fwd_kernel(const f32x4* __restrict__ x4,
                     const float* __restrict__ decay,
                     const float* __restrict__ vth,
                     f32x4* __restrict__ out4)
{
    __shared__ float xs[2 * CT * D_FEAT];   // 8 KB: [2 rows][CT][D]
    __shared__ float ss[2 * CT * D_FEAT];   // 8 KB spikes

    const int tid  = threadIdx.x;
    const int lrow = tid >> 7;              // 0/1: which of the block's rows
    const int d    = tid & (D_FEAT - 1);    // feature index
    const int r0   = blockIdx.x * 2;        // first row of this block

    // per-feature constants (2 expf per thread -- negligible)
    const float dec = 1.0f / (1.0f + expf(-decay[d]));
    const float th  = 1.0f / (1.0f + expf(-vth[d])) + 0.1f;

    const size_t rowq = (size_t)T_STEPS * D_FEAT / 4;   // float4s per row

    float v = 0.0f;

    for (int c = 0; c < NCHUNK; ++c) {
        const size_t cq = (size_t)(c * CT) * D_FEAT / 4; // chunk offset (float4)

        // ---- stage x: 2 rounds of fully-contiguous 4KB float4 loads ----
#pragma unroll
        for (int p = 0; p < 2; ++p) {
            const f32x4 tmp = __builtin_nontemporal_load(
                x4 + (size_t)(r0 + p) * rowq + cq + (size_t)tid);
            *(f32x4*)&xs[p * (CT * D_FEAT) + tid * 4] = tmp;
        }
        __syncthreads();

        // ---- compute CT steps of this thread's (row, d) chain ----
#pragma unroll
        for (int i = 0; i < CT; ++i) {
            const float xv = xs[lrow * (CT * D_FEAT) + i * D_FEAT + d];
            v = __fadd_rn(__fmul_rn(v, dec), xv);
            const bool f = (v > th);
            ss[lrow * (CT * D_FEAT) + i * D_FEAT + d] = f ? 1.0f : 0.0f;
            v = f ? 0.0f : v;
        }
        __syncthreads();

        // ---- store spikes: 2 rounds of contiguous float4 stores ----
        // (no trailing barrier: next stage overwrites xs, which no wave
        //  reads after the compute barrier; next compute writes ss only
        //  after the next stage barrier, and each wave's ss reads complete
        //  into registers before it reaches that barrier)
#pragma unroll
        for (int p = 0; p < 2; ++p) {
            const f32x4 sv = *(const f32x4*)&ss[p * (CT * D_FEAT) + tid * 4];
            __builtin_nontemporal_store(sv,
                out4 + (size_t)(r0 + p) * rowq + cq + (size_t)tid);
        }
    }
}

extern "C" void kernel_launch(void* const* d_in, const int* in_sizes, int n_in,
                              void* d_out, int out_size, void* d_ws, size_t ws_size,
                              hipStream_t stream)
{
    const float* x     = (const float*)d_in[0];
    const float* decay = (const float*)d_in[1];
    const float* vth   = (const float*)d_in[2];
    float*       out   = (float*)d_out;

    const int total  = in_sizes[0];                    // B*N*T*D = 67108864
    const int rows   = total / (T_STEPS * D_FEAT);     // B*N = 4096
    const int blocks = rows / 2;                       // 2048
    const int block  = 256;

    plif_fwd_kernel<<<blocks, block, 0, stream>>>(
        (const f32x4*)x, decay, vth, (f32x4*)out);
}